// Round 16
// baseline (336.360 us; speedup 1.0000x reference)
//
#include <hip/hip_runtime.h>

// ResidualVQ: B=8, T=2048, D=256, Q=8, K=1024. N = B*T = 16384.
// Scoring via fp16 split-MFMA: 2x = xh + xl, e = eh + el (fp16 RTNE).
// 2x.e ~= xh.eh + xh.el + xl.eh  (dropped xl.el ~ 2e-6, below fp32 noise).
// score = acc - |e|^2  (row-constant |x|^2 dropped; same argmax).
//
// ROUND 16 = round 14 (verified, 289us) + ONE fix: the B-build ds_write
// bank conflicts (7.35M measured). r14 wrote slot qd^s with s wave-uniform
// and qd loop-constant -> every ds_write_b128 instruction had all 64 lanes
// on 2 of 8 bank-quads (32-way). Per-lane write-order permutation
// qd = j ^ (ud&3) keeps the (data -> address) mapping IDENTICAL (bijection;
// element-simulated) but spreads each instruction across 8 ranges (8-way).
// r15's direct-global-A experiment is reverted (unlocalized index flips).
//
// d_out (float): [0, N*D) quantized_out; [N*D,+Q*N) indices; [+Q) losses
// d_ws: ecat f16[Q*K][512] | norms f32[Q*K]

typedef _Float16 f16;
typedef f16 f16x8 __attribute__((ext_vector_type(8)));
typedef float f32x16 __attribute__((ext_vector_type(16)));

constexpr int Dd = 256;
constexpr int Kk = 1024;
constexpr int Qq = 8;
constexpr int Nn = 16384;

__device__ inline void gload16(const f16* g, f16* l) {
    __builtin_amdgcn_global_load_lds(
        (const __attribute__((address_space(1))) unsigned int*)(const __attribute__((address_space(1))) f16*)g,
        (__attribute__((address_space(3))) unsigned int*)(__attribute__((address_space(3))) f16*)l,
        16, 0, 0);
}

// ---- build ecat[Q*K][512] = [eh|el] + squared norms, from fp32 codebooks ----
__global__ __launch_bounds__(256) void build_ecat(const float* __restrict__ cb,
                                                  f16* __restrict__ ecat,
                                                  float* __restrict__ norms) {
    int row = blockIdx.x * 8 + (threadIdx.x >> 5);
    int p = threadIdx.x & 31;
    const float* s = cb + (size_t)row * Dd + p * 8;
    f16x8 hi, lo;
    float sq = 0.f;
#pragma unroll
    for (int j = 0; j < 8; ++j) {
        float v = s[j];
        f16 h = (f16)v;
        hi[j] = h; lo[j] = (f16)(v - (float)h);
        sq = fmaf(v, v, sq);
    }
    *(f16x8*)(ecat + (size_t)row * 512 + p * 8) = hi;
    *(f16x8*)(ecat + (size_t)row * 512 + 256 + p * 8) = lo;
#pragma unroll
    for (int off = 16; off >= 1; off >>= 1) sq += __shfl_down(sq, off, 32);
    if (p == 0) norms[row] = sq;
}

// ---- the whole RVQ, one launch: block = 64 tokens through all 8 layers ----
__global__ __launch_bounds__(512, 2) void rvq_kernel(
    const float* __restrict__ x,      // [N][256]
    const float* __restrict__ cbs,    // [Q][K][256] fp32
    const f16* __restrict__ ecat,     // [Q*K][512]
    const float* __restrict__ norms,  // [Q*K]
    float* __restrict__ outq,         // d_out [N][256]
    float* __restrict__ idxs,         // d_out [Q][N] (as float)
    float* __restrict__ losses)       // d_out [Q]
{
    __shared__ f16 sA[2][16384];      // dbuf: [0,8192)=eh 256rx32c, [8192,16384)=el
    __shared__ f16 sB[32768];         // 16 sub-tiles [64r][32c]: 0-7 xh, 8-15 xl
    __shared__ float smn[1024];
    __shared__ float2 smg[4][64];
    __shared__ int bestk[64];
    __shared__ float lred[8];

    const int tid = threadIdx.x;
    const int w = tid >> 6, l = tid & 63;
    const int l32 = l & 31, lh = l >> 5;
    const int wcq = w >> 1;           // code quad 0..3 (64 codes each per cs)
    const int wt = w & 1;             // token half 0..1 (32 tokens each)
    const int tbase = blockIdx.x * 64;
    const int ut = tid >> 3, ud = tid & 7;   // token 0..63, dim-group 0..7
    const int grow = tbase + ut;

    // A staging geometry (r13 pattern): thread t -> rows tid>>2 (+128),
    // source col-chunk pre-swizzled with s(row)=(row>>3)&3 = (tid>>5)&3.
    const int srow = tid >> 2;
    const int g = ((tid & 3) ^ ((tid >> 5) & 3)) * 8;

    // ds_read offsets (global chunk qd=kh*2+lh read at slot qd^s(row))
    int offA_[2][2];
#pragma unroll
    for (int m = 0; m < 2; ++m)
#pragma unroll
        for (int kh = 0; kh < 2; ++kh) {
            int row = wcq * 64 + m * 32 + l32;
            offA_[m][kh] = row * 32 + (((kh * 2 + lh) ^ ((row >> 3) & 3)) * 8);
        }
    int rbh[2];
#pragma unroll
    for (int kh = 0; kh < 2; ++kh) {
        int row = wt * 32 + l32;
        rbh[kh] = row * 32 + (((kh * 2 + lh) ^ ((row >> 3) & 3)) * 8);
    }

    float r[32];   // residual: token ut, dims ud*32 .. ud*32+31

#define STAGE(P, pp, c) do { \
        const f16* ga_ = gqs + (size_t)(pp) * 131072 + (c) * 32; \
        gload16(ga_,                  &sA[P][tid * 8]); \
        gload16(ga_ + 128 * 512,      &sA[P][4096 + tid * 8]); \
        gload16(ga_ + 256,            &sA[P][8192 + tid * 8]); \
        gload16(ga_ + 256 + 128 * 512,&sA[P][12288 + tid * 8]); \
    } while (0)

#pragma unroll 1
    for (int q = 0; q < Qq; ++q) {
        const f16* gqs = ecat + ((size_t)q * Kk + srow) * 512 + g;
        // prestage A(p=0, c0,c1): latency hides under the update phase
        STAGE(0, 0, 0);
        STAGE(1, 0, 1);

        // ---- update phase (residual in registers) ----
        float lp = 0.f;
        if (q == 0) {
            const float4* xs = (const float4*)(x + (size_t)grow * Dd + ud * 32);
#pragma unroll
            for (int jv = 0; jv < 8; ++jv) {
                float4 v = xs[jv];
                r[jv * 4 + 0] = v.x; r[jv * 4 + 1] = v.y;
                r[jv * 4 + 2] = v.z; r[jv * 4 + 3] = v.w;
            }
        } else {
            const int k = bestk[ut];
            const float4* e4 = (const float4*)(cbs + ((size_t)(q - 1) * Kk + k) * Dd + ud * 32);
#pragma unroll
            for (int jv = 0; jv < 8; ++jv) {
                float4 v = e4[jv];
                r[jv * 4 + 0] -= v.x; r[jv * 4 + 1] -= v.y;
                r[jv * 4 + 2] -= v.z; r[jv * 4 + 3] -= v.w;
            }
#pragma unroll
            for (int j = 0; j < 32; ++j) lp = fmaf(r[j], r[j], lp);
            if ((tid & 7) == 0) idxs[(size_t)(q - 1) * Nn + grow] = (float)k;
#pragma unroll
            for (int off = 32; off >= 1; off >>= 1) lp += __shfl_down(lp, off);
            if (l == 0) lred[w] = lp;
        }
        // ---- build B tile in LDS: split(2r) -> xh sub-tile ud, xl 8+ud.
        //      Per-lane qd order j^(ud&3): each ds_write_b128 instruction
        //      spreads lanes across slots (r14 was wave-constant -> 32-way).
        {
            const int s = (ut >> 3) & 3;
#pragma unroll
            for (int j = 0; j < 4; ++j) {
                const int qd = j ^ (ud & 3);
                f16x8 hi, lo;
#pragma unroll
                for (int j2 = 0; j2 < 8; ++j2) {
                    float v = 2.f * r[qd * 8 + j2];
                    f16 h = (f16)v;
                    hi[j2] = h; lo[j2] = (f16)(v - (float)h);
                }
                int a = ud * 2048 + ut * 32 + ((qd ^ s) * 8);
                *(f16x8*)&sB[a] = hi;
                *(f16x8*)&sB[16384 + a] = lo;
            }
        }
        smn[tid] = norms[q * Kk + tid];
        smn[512 + tid] = norms[q * Kk + 512 + tid];
        __syncthreads();   // full drain: sB writes, prestaged A, global stores
        if (q > 0 && tid == 0) {
            float s2 = 0.f;
#pragma unroll
            for (int i = 0; i < 8; ++i) s2 += lred[i];
            atomicAdd(losses + q - 1, s2 * (1.0f / ((float)Nn * (float)Dd)));
        }

        // ---- GEMM: 4 cs passes x 256 codes x 8 chunks ----
        float bv = -3.4e38f; int bi = 0;
#pragma unroll 1
        for (int p = 0; p < 4; ++p) {
            f32x16 acc[2] = {};
#pragma unroll
            for (int c = 0; c < 8; ++c) {
                const int P = c & 1;
                if (c >= 1 && c < 7) STAGE(P ^ 1, p, c + 1);
#pragma unroll
                for (int kh = 0; kh < 2; ++kh) {
                    f16x8 a0 = *(const f16x8*)&sA[P][offA_[0][kh]];
                    f16x8 a1 = *(const f16x8*)&sA[P][offA_[1][kh]];
                    f16x8 bh = *(const f16x8*)&sB[c * 2048 + rbh[kh]];
                    f16x8 bl = *(const f16x8*)&sB[16384 + c * 2048 + rbh[kh]];
                    __builtin_amdgcn_s_setprio(1);
                    acc[0] = __builtin_amdgcn_mfma_f32_32x32x16_f16(a0, bh, acc[0], 0, 0, 0);
                    acc[1] = __builtin_amdgcn_mfma_f32_32x32x16_f16(a1, bh, acc[1], 0, 0, 0);
                    acc[0] = __builtin_amdgcn_mfma_f32_32x32x16_f16(a0, bl, acc[0], 0, 0, 0);
                    acc[1] = __builtin_amdgcn_mfma_f32_32x32x16_f16(a1, bl, acc[1], 0, 0, 0);
                    __builtin_amdgcn_s_setprio(0);
                    f16x8 e0 = *(const f16x8*)&sA[P][8192 + offA_[0][kh]];
                    f16x8 e1 = *(const f16x8*)&sA[P][8192 + offA_[1][kh]];
                    __builtin_amdgcn_s_setprio(1);
                    acc[0] = __builtin_amdgcn_mfma_f32_32x32x16_f16(e0, bh, acc[0], 0, 0, 0);
                    acc[1] = __builtin_amdgcn_mfma_f32_32x32x16_f16(e1, bh, acc[1], 0, 0, 0);
                    __builtin_amdgcn_s_setprio(0);
                }
                if (c < 7)
                    asm volatile("s_waitcnt vmcnt(0)\n\ts_barrier" ::: "memory");
            }
            asm volatile("s_barrier" ::: "memory");   // fence chunk-7 reads
            if (p < 3) { STAGE(0, p + 1, 0); STAGE(1, p + 1, 1); }
            // epilogue (overlaps next-cs staging latency); ascending code order
#pragma unroll
            for (int m = 0; m < 2; ++m) {
#pragma unroll
                for (int rr = 0; rr < 16; ++rr) {
                    int cl = wcq * 64 + m * 32 + (rr & 3) + 8 * (rr >> 2) + 4 * lh;
                    float v = acc[m][rr] - smn[p * 256 + cl];
                    int cg = p * 256 + cl;
                    if (v > bv) { bv = v; bi = cg; }
                }
            }
            if (p < 3)
                asm volatile("s_waitcnt vmcnt(4)\n\ts_barrier" ::: "memory");
        }
        // ---- merge: lanes l<->l^32 (same token), then the 4 code-quad waves ----
        {
            float ov = __shfl_xor(bv, 32);
            int oi = __shfl_xor(bi, 32);
            if (ov > bv || (ov == bv && oi < bi)) { bv = ov; bi = oi; }
            if (l < 32) smg[wcq][wt * 32 + l] = make_float2(bv, (float)bi);
            __syncthreads();
            if (tid < 64) {
                float2 r2 = smg[0][tid];
#pragma unroll
                for (int ww = 1; ww < 4; ++ww) {
                    float2 c2 = smg[ww][tid];
                    if (c2.x > r2.x || (c2.x == r2.x && c2.y < r2.y)) r2 = c2;
                }
                bestk[tid] = (int)r2.y;
            }
            __syncthreads();
        }
    }
#undef STAGE

    // ---- final: subtract e7, loss7, idx7, out = x - r8 ----
    {
        const int k = bestk[ut];
        const float4* e4 = (const float4*)(cbs + ((size_t)7 * Kk + k) * Dd + ud * 32);
        float lp = 0.f;
#pragma unroll
        for (int jv = 0; jv < 8; ++jv) {
            float4 v = e4[jv];
            r[jv * 4 + 0] -= v.x; r[jv * 4 + 1] -= v.y;
            r[jv * 4 + 2] -= v.z; r[jv * 4 + 3] -= v.w;
        }
#pragma unroll
        for (int j = 0; j < 32; ++j) lp = fmaf(r[j], r[j], lp);
        const float4* xs = (const float4*)(x + (size_t)grow * Dd + ud * 32);
        float4* os = (float4*)(outq + (size_t)grow * Dd + ud * 32);
#pragma unroll
        for (int jv = 0; jv < 8; ++jv) {
            float4 xv = xs[jv];
            float4 o;
            o.x = xv.x - r[jv * 4 + 0]; o.y = xv.y - r[jv * 4 + 1];
            o.z = xv.z - r[jv * 4 + 2]; o.w = xv.w - r[jv * 4 + 3];
            os[jv] = o;
        }
        if ((tid & 7) == 0) idxs[(size_t)7 * Nn + grow] = (float)k;
#pragma unroll
        for (int off = 32; off >= 1; off >>= 1) lp += __shfl_down(lp, off);
        if (l == 0) lred[w] = lp;
        __syncthreads();
        if (tid == 0) {
            float s2 = 0.f;
#pragma unroll
            for (int i = 0; i < 8; ++i) s2 += lred[i];
            atomicAdd(losses + 7, s2 * (1.0f / ((float)Nn * (float)Dd)));
        }
    }
}

extern "C" void kernel_launch(void* const* d_in, const int* in_sizes, int n_in,
                              void* d_out, int out_size, void* d_ws, size_t ws_size,
                              hipStream_t stream) {
    const float* x   = (const float*)d_in[0];   // [N,D]
    const float* cbs = (const float*)d_in[1];   // [Q,K,D]
    float* out    = (float*)d_out;
    float* idxs   = out + (size_t)Nn * Dd;        // [Q*N]
    float* losses = idxs + (size_t)Qq * Nn;       // [Q]

    f16* ecat    = (f16*)d_ws;                          // [Q*K][512]
    float* norms = (float*)(ecat + (size_t)Qq * Kk * 512);  // [Q*K]

    hipMemsetAsync(losses, 0, Qq * sizeof(float), stream);
    build_ecat<<<(Qq * Kk) / 8, 256, 0, stream>>>(cbs, ecat, norms);
    rvq_kernel<<<Nn / 64, 512, 0, stream>>>(x, cbs, ecat, norms,
                                            out, idxs, losses);
}

// Round 17
// 284.321 us; speedup vs baseline: 1.1830x; 1.1830x over previous
//
#include <hip/hip_runtime.h>

// ResidualVQ: B=8, T=2048, D=256, Q=8, K=1024. N = B*T = 16384.
// Scoring via fp16 split-MFMA: 2x = xh + xl, e = eh + el (fp16 RTNE).
// 2x.e ~= xh.eh + xh.el + xl.eh  (dropped xl.el ~ 2e-6, below fp32 noise).
// score = acc - |e|^2  (row-constant |x|^2 dropped; same argmax).
//
// ROUND 17 = round 14 (verified 289us) + ADDRESS-ONLY B-write conflict fix.
// r16's lesson: permuting the register READ ORDER (qd = j^(ud&3)) made
// r[qd*8+j2] runtime-indexed -> scratch (rule #20; VALUBusy 13->26%).
// Here qd stays the compile-time loop var; the lane spread moves into the
// SLOT function: write slot = qd ^ s ^ (ud&3), read slot ^= (c&3) (c = ud
// at write time; compile-time in the unrolled GEMM loop -> rbh[4][2] with
// constant index). Write quads: 8x8 lanes = bandwidth floor (was 2x32).
//
// d_out (float): [0, N*D) quantized_out; [N*D,+Q*N) indices; [+Q) losses
// d_ws: ecat f16[Q*K][512] | norms f32[Q*K]

typedef _Float16 f16;
typedef f16 f16x8 __attribute__((ext_vector_type(8)));
typedef float f32x16 __attribute__((ext_vector_type(16)));

constexpr int Dd = 256;
constexpr int Kk = 1024;
constexpr int Qq = 8;
constexpr int Nn = 16384;

__device__ inline void gload16(const f16* g, f16* l) {
    __builtin_amdgcn_global_load_lds(
        (const __attribute__((address_space(1))) unsigned int*)(const __attribute__((address_space(1))) f16*)g,
        (__attribute__((address_space(3))) unsigned int*)(__attribute__((address_space(3))) f16*)l,
        16, 0, 0);
}

// ---- build ecat[Q*K][512] = [eh|el] + squared norms, from fp32 codebooks ----
__global__ __launch_bounds__(256) void build_ecat(const float* __restrict__ cb,
                                                  f16* __restrict__ ecat,
                                                  float* __restrict__ norms) {
    int row = blockIdx.x * 8 + (threadIdx.x >> 5);
    int p = threadIdx.x & 31;
    const float* s = cb + (size_t)row * Dd + p * 8;
    f16x8 hi, lo;
    float sq = 0.f;
#pragma unroll
    for (int j = 0; j < 8; ++j) {
        float v = s[j];
        f16 h = (f16)v;
        hi[j] = h; lo[j] = (f16)(v - (float)h);
        sq = fmaf(v, v, sq);
    }
    *(f16x8*)(ecat + (size_t)row * 512 + p * 8) = hi;
    *(f16x8*)(ecat + (size_t)row * 512 + 256 + p * 8) = lo;
#pragma unroll
    for (int off = 16; off >= 1; off >>= 1) sq += __shfl_down(sq, off, 32);
    if (p == 0) norms[row] = sq;
}

// ---- the whole RVQ, one launch: block = 64 tokens through all 8 layers ----
__global__ __launch_bounds__(512, 2) void rvq_kernel(
    const float* __restrict__ x,      // [N][256]
    const float* __restrict__ cbs,    // [Q][K][256] fp32
    const f16* __restrict__ ecat,     // [Q*K][512]
    const float* __restrict__ norms,  // [Q*K]
    float* __restrict__ outq,         // d_out [N][256]
    float* __restrict__ idxs,         // d_out [Q][N] (as float)
    float* __restrict__ losses)       // d_out [Q]
{
    __shared__ f16 sA[2][16384];      // dbuf: [0,8192)=eh 256rx32c, [8192,16384)=el
    __shared__ f16 sB[32768];         // 16 sub-tiles [64r][32c]: 0-7 xh, 8-15 xl
    __shared__ float smn[1024];
    __shared__ float2 smg[4][64];
    __shared__ int bestk[64];
    __shared__ float lred[8];

    const int tid = threadIdx.x;
    const int w = tid >> 6, l = tid & 63;
    const int l32 = l & 31, lh = l >> 5;
    const int wcq = w >> 1;           // code quad 0..3 (64 codes each per cs)
    const int wt = w & 1;             // token half 0..1 (32 tokens each)
    const int tbase = blockIdx.x * 64;
    const int ut = tid >> 3, ud = tid & 7;   // token 0..63, dim-group 0..7
    const int grow = tbase + ut;

    // A staging geometry (r13 pattern): thread t -> rows tid>>2 (+128),
    // source col-chunk pre-swizzled with s(row)=(row>>3)&3 = (tid>>5)&3.
    const int srow = tid >> 2;
    const int g = ((tid & 3) ^ ((tid >> 5) & 3)) * 8;

    // A ds_read offsets (global chunk qd=kh*2+lh read at slot qd^s(row))
    int offA_[2][2];
#pragma unroll
    for (int m = 0; m < 2; ++m)
#pragma unroll
        for (int kh = 0; kh < 2; ++kh) {
            int row = wcq * 64 + m * 32 + l32;
            offA_[m][kh] = row * 32 + (((kh * 2 + lh) ^ ((row >> 3) & 3)) * 8);
        }
    // B ds_read offsets: slot additionally XORed with (c&3); c is compile-time
    // in the unrolled chunk loop -> rbh[c&3][kh] is a constant index.
    int rbh[4][2];
#pragma unroll
    for (int cc = 0; cc < 4; ++cc)
#pragma unroll
        for (int kh = 0; kh < 2; ++kh) {
            int row = wt * 32 + l32;
            rbh[cc][kh] = row * 32 + ((((kh * 2 + lh) ^ ((row >> 3) & 3)) ^ cc) * 8);
        }

    float r[32];   // residual: token ut, dims ud*32 .. ud*32+31

#define STAGE(P, pp, c) do { \
        const f16* ga_ = gqs + (size_t)(pp) * 131072 + (c) * 32; \
        gload16(ga_,                  &sA[P][tid * 8]); \
        gload16(ga_ + 128 * 512,      &sA[P][4096 + tid * 8]); \
        gload16(ga_ + 256,            &sA[P][8192 + tid * 8]); \
        gload16(ga_ + 256 + 128 * 512,&sA[P][12288 + tid * 8]); \
    } while (0)

#pragma unroll 1
    for (int q = 0; q < Qq; ++q) {
        const f16* gqs = ecat + ((size_t)q * Kk + srow) * 512 + g;
        // prestage A(p=0, c0,c1): latency hides under the update phase
        STAGE(0, 0, 0);
        STAGE(1, 0, 1);

        // ---- update phase (residual in registers) ----
        float lp = 0.f;
        if (q == 0) {
            const float4* xs = (const float4*)(x + (size_t)grow * Dd + ud * 32);
#pragma unroll
            for (int jv = 0; jv < 8; ++jv) {
                float4 v = xs[jv];
                r[jv * 4 + 0] = v.x; r[jv * 4 + 1] = v.y;
                r[jv * 4 + 2] = v.z; r[jv * 4 + 3] = v.w;
            }
        } else {
            const int k = bestk[ut];
            const float4* e4 = (const float4*)(cbs + ((size_t)(q - 1) * Kk + k) * Dd + ud * 32);
#pragma unroll
            for (int jv = 0; jv < 8; ++jv) {
                float4 v = e4[jv];
                r[jv * 4 + 0] -= v.x; r[jv * 4 + 1] -= v.y;
                r[jv * 4 + 2] -= v.z; r[jv * 4 + 3] -= v.w;
            }
#pragma unroll
            for (int j = 0; j < 32; ++j) lp = fmaf(r[j], r[j], lp);
            if ((tid & 7) == 0) idxs[(size_t)(q - 1) * Nn + grow] = (float)k;
#pragma unroll
            for (int off = 32; off >= 1; off >>= 1) lp += __shfl_down(lp, off);
            if (l == 0) lred[w] = lp;
        }
        // ---- build B tile in LDS: split(2r) -> xh sub-tile ud, xl 8+ud.
        //      qd = j (compile-time: no runtime register indexing, r16 lesson);
        //      lane spread via slot ^= (ud&3): write quads 8x8 = BW floor.
        {
            const int s = (ut >> 3) & 3;
#pragma unroll
            for (int qd = 0; qd < 4; ++qd) {
                f16x8 hi, lo;
#pragma unroll
                for (int j2 = 0; j2 < 8; ++j2) {
                    float v = 2.f * r[qd * 8 + j2];
                    f16 h = (f16)v;
                    hi[j2] = h; lo[j2] = (f16)(v - (float)h);
                }
                int a = ud * 2048 + ut * 32 + ((((qd ^ s) ^ (ud & 3)) & 3) * 8);
                *(f16x8*)&sB[a] = hi;
                *(f16x8*)&sB[16384 + a] = lo;
            }
        }
        smn[tid] = norms[q * Kk + tid];
        smn[512 + tid] = norms[q * Kk + 512 + tid];
        __syncthreads();   // full drain: sB writes, prestaged A, global stores
        if (q > 0 && tid == 0) {
            float s2 = 0.f;
#pragma unroll
            for (int i = 0; i < 8; ++i) s2 += lred[i];
            atomicAdd(losses + q - 1, s2 * (1.0f / ((float)Nn * (float)Dd)));
        }

        // ---- GEMM: 4 cs passes x 256 codes x 8 chunks ----
        float bv = -3.4e38f; int bi = 0;
#pragma unroll 1
        for (int p = 0; p < 4; ++p) {
            f32x16 acc[2] = {};
#pragma unroll
            for (int c = 0; c < 8; ++c) {
                const int P = c & 1;
                if (c >= 1 && c < 7) STAGE(P ^ 1, p, c + 1);
#pragma unroll
                for (int kh = 0; kh < 2; ++kh) {
                    f16x8 a0 = *(const f16x8*)&sA[P][offA_[0][kh]];
                    f16x8 a1 = *(const f16x8*)&sA[P][offA_[1][kh]];
                    f16x8 bh = *(const f16x8*)&sB[c * 2048 + rbh[c & 3][kh]];
                    f16x8 bl = *(const f16x8*)&sB[16384 + c * 2048 + rbh[c & 3][kh]];
                    __builtin_amdgcn_s_setprio(1);
                    acc[0] = __builtin_amdgcn_mfma_f32_32x32x16_f16(a0, bh, acc[0], 0, 0, 0);
                    acc[1] = __builtin_amdgcn_mfma_f32_32x32x16_f16(a1, bh, acc[1], 0, 0, 0);
                    acc[0] = __builtin_amdgcn_mfma_f32_32x32x16_f16(a0, bl, acc[0], 0, 0, 0);
                    acc[1] = __builtin_amdgcn_mfma_f32_32x32x16_f16(a1, bl, acc[1], 0, 0, 0);
                    __builtin_amdgcn_s_setprio(0);
                    f16x8 e0 = *(const f16x8*)&sA[P][8192 + offA_[0][kh]];
                    f16x8 e1 = *(const f16x8*)&sA[P][8192 + offA_[1][kh]];
                    __builtin_amdgcn_s_setprio(1);
                    acc[0] = __builtin_amdgcn_mfma_f32_32x32x16_f16(e0, bh, acc[0], 0, 0, 0);
                    acc[1] = __builtin_amdgcn_mfma_f32_32x32x16_f16(e1, bh, acc[1], 0, 0, 0);
                    __builtin_amdgcn_s_setprio(0);
                }
                if (c < 7)
                    asm volatile("s_waitcnt vmcnt(0)\n\ts_barrier" ::: "memory");
            }
            asm volatile("s_barrier" ::: "memory");   // fence chunk-7 reads
            if (p < 3) { STAGE(0, p + 1, 0); STAGE(1, p + 1, 1); }
            // epilogue (overlaps next-cs staging latency); ascending code order
#pragma unroll
            for (int m = 0; m < 2; ++m) {
#pragma unroll
                for (int rr = 0; rr < 16; ++rr) {
                    int cl = wcq * 64 + m * 32 + (rr & 3) + 8 * (rr >> 2) + 4 * lh;
                    float v = acc[m][rr] - smn[p * 256 + cl];
                    int cg = p * 256 + cl;
                    if (v > bv) { bv = v; bi = cg; }
                }
            }
            if (p < 3)
                asm volatile("s_waitcnt vmcnt(4)\n\ts_barrier" ::: "memory");
        }
        // ---- merge: lanes l<->l^32 (same token), then the 4 code-quad waves ----
        {
            float ov = __shfl_xor(bv, 32);
            int oi = __shfl_xor(bi, 32);
            if (ov > bv || (ov == bv && oi < bi)) { bv = ov; bi = oi; }
            if (l < 32) smg[wcq][wt * 32 + l] = make_float2(bv, (float)bi);
            __syncthreads();
            if (tid < 64) {
                float2 r2 = smg[0][tid];
#pragma unroll
                for (int ww = 1; ww < 4; ++ww) {
                    float2 c2 = smg[ww][tid];
                    if (c2.x > r2.x || (c2.x == r2.x && c2.y < r2.y)) r2 = c2;
                }
                bestk[tid] = (int)r2.y;
            }
            __syncthreads();
        }
    }
#undef STAGE

    // ---- final: subtract e7, loss7, idx7, out = x - r8 ----
    {
        const int k = bestk[ut];
        const float4* e4 = (const float4*)(cbs + ((size_t)7 * Kk + k) * Dd + ud * 32);
        float lp = 0.f;
#pragma unroll
        for (int jv = 0; jv < 8; ++jv) {
            float4 v = e4[jv];
            r[jv * 4 + 0] -= v.x; r[jv * 4 + 1] -= v.y;
            r[jv * 4 + 2] -= v.z; r[jv * 4 + 3] -= v.w;
        }
#pragma unroll
        for (int j = 0; j < 32; ++j) lp = fmaf(r[j], r[j], lp);
        const float4* xs = (const float4*)(x + (size_t)grow * Dd + ud * 32);
        float4* os = (float4*)(outq + (size_t)grow * Dd + ud * 32);
#pragma unroll
        for (int jv = 0; jv < 8; ++jv) {
            float4 xv = xs[jv];
            float4 o;
            o.x = xv.x - r[jv * 4 + 0]; o.y = xv.y - r[jv * 4 + 1];
            o.z = xv.z - r[jv * 4 + 2]; o.w = xv.w - r[jv * 4 + 3];
            os[jv] = o;
        }
        if ((tid & 7) == 0) idxs[(size_t)7 * Nn + grow] = (float)k;
#pragma unroll
        for (int off = 32; off >= 1; off >>= 1) lp += __shfl_down(lp, off);
        if (l == 0) lred[w] = lp;
        __syncthreads();
        if (tid == 0) {
            float s2 = 0.f;
#pragma unroll
            for (int i = 0; i < 8; ++i) s2 += lred[i];
            atomicAdd(losses + 7, s2 * (1.0f / ((float)Nn * (float)Dd)));
        }
    }
}

extern "C" void kernel_launch(void* const* d_in, const int* in_sizes, int n_in,
                              void* d_out, int out_size, void* d_ws, size_t ws_size,
                              hipStream_t stream) {
    const float* x   = (const float*)d_in[0];   // [N,D]
    const float* cbs = (const float*)d_in[1];   // [Q,K,D]
    float* out    = (float*)d_out;
    float* idxs   = out + (size_t)Nn * Dd;        // [Q*N]
    float* losses = idxs + (size_t)Qq * Nn;       // [Q]

    f16* ecat    = (f16*)d_ws;                          // [Q*K][512]
    float* norms = (float*)(ecat + (size_t)Qq * Kk * 512);  // [Q*K]

    hipMemsetAsync(losses, 0, Qq * sizeof(float), stream);
    build_ecat<<<(Qq * Kk) / 8, 256, 0, stream>>>(cbs, ecat, norms);
    rvq_kernel<<<Nn / 64, 512, 0, stream>>>(x, cbs, ecat, norms,
                                            out, idxs, losses);
}